// Round 2
// baseline (96.044 us; speedup 1.0000x reference)
//
#include <hip/hip_runtime.h>

// QuantumAttention: B=8, S=2048, E=8, H=2, D=4, NQ=8
//
// Round 2 restructure: the round-1 kernel was LDS-return-BW bound (each wave
// broadcast-read the full 64KB K/V; 2 blk x 8 waves x 256 iters x 2 ds_read_b128
// x 12cyc = 98K cyc/CU = 41us, matching the ~38us measured). Now the inner loop
// uses NO memory at all: each lane computes K/V for one j into registers, and
// v_readlane broadcasts lane t's K/V to SGPRs; each lane applies them to R=4
// query rows held in registers. VALU floor ~10us.
//
// Quantum circuit is closed-form: c_w = cos(tok[w]+tok[w%4]);
// z[0]=c1..c7, z[q>=1]=c0..cq.  Softmax is one-pass (|score|<~8, fp32 safe).

#define SS 2048
#define EE 8

__device__ __forceinline__ float rl(float v, int t) {
    return __int_as_float(__builtin_amdgcn_readlane(__float_as_int(v), t));
}

// grid 512: bid = b<<6 | h<<5 | rt<<2 | jq ; 256 threads = 4 waves.
// wave w handles j-slice [jq*512 + w*128, +128); lane owns rows rt*256+lane+{0,64,128,192}.
// Partials (den, acc4) per row per 128-j slice -> ws (16 slices/row).
extern "C" __global__ __launch_bounds__(256)
void qa_attn2(const float* __restrict__ x, const float* __restrict__ Wq,
              const float* __restrict__ Wk, const float* __restrict__ Wv,
              float* __restrict__ wsD, float4* __restrict__ wsA) {
    __shared__ float wrow[96];   // wq' (pre-scaled), wk, wv rows for this head
    const int bid = blockIdx.x;
    const int jq = bid & 3, rt = (bid >> 2) & 7, h = (bid >> 5) & 1, b = bid >> 6;
    const int tid = threadIdx.x, lane = tid & 63, w = tid >> 6;

    if (tid < 96) {
        const int grp = tid >> 5, d = (tid >> 3) & 3, e = tid & 7;
        const float* W = (grp == 0) ? Wq : (grp == 1 ? Wk : Wv);
        float val = W[(h * 4 + d) * EE + e];
        if (grp == 0) val *= 0.72134752044f;   // 0.5 (1/sqrt(D)) * log2(e) -> bare v_exp_f32
        wrow[tid] = val;
    }
    __syncthreads();

    // q' for this lane's 4 rows
    float q[4][4];
    const int row0 = rt * 256 + lane;
    #pragma unroll
    for (int m = 0; m < 4; ++m) {
        const float* xp = x + ((size_t)(b * SS + row0 + m * 64)) * EE;
        float xv[8];
        *(float4*)&xv[0] = *(const float4*)xp;
        *(float4*)&xv[4] = *(const float4*)(xp + 4);
        #pragma unroll
        for (int d = 0; d < 4; ++d) {
            float s = 0.f;
            #pragma unroll
            for (int e = 0; e < 8; ++e) s += xv[e] * wrow[d * 8 + e];
            q[m][d] = s;
        }
    }

    float den[4] = {0.f, 0.f, 0.f, 0.f};
    float acc[4][4] = {};

    const int jbase = jq * 512 + w * 128;
    #pragma unroll 1
    for (int g = 0; g < 2; ++g) {
        // this lane's K/V for j = jbase + g*64 + lane (registers only)
        const int myj = jbase + g * 64 + lane;
        const float* xp = x + ((size_t)(b * SS + myj)) * EE;
        float xv[8];
        *(float4*)&xv[0] = *(const float4*)xp;
        *(float4*)&xv[4] = *(const float4*)(xp + 4);
        float mk[4], mv[4];
        #pragma unroll
        for (int d = 0; d < 4; ++d) {
            float sk = 0.f, sv = 0.f;
            #pragma unroll
            for (int e = 0; e < 8; ++e) {
                sk += xv[e] * wrow[32 + d * 8 + e];
                sv += xv[e] * wrow[64 + d * 8 + e];
            }
            mk[d] = sk; mv[d] = sv;
        }
        // 64 steps: broadcast lane t's K/V via readlane (SGPRs), apply to 4 rows
        #pragma unroll 16
        for (int t = 0; t < 64; ++t) {
            const float k0 = rl(mk[0], t), k1 = rl(mk[1], t),
                        k2 = rl(mk[2], t), k3 = rl(mk[3], t);
            const float v0 = rl(mv[0], t), v1 = rl(mv[1], t),
                        v2 = rl(mv[2], t), v3 = rl(mv[3], t);
            #pragma unroll
            for (int m = 0; m < 4; ++m) {
                const float s = q[m][0] * k0 + q[m][1] * k1 + q[m][2] * k2 + q[m][3] * k3;
                const float e = __builtin_amdgcn_exp2f(s);
                den[m] += e;
                acc[m][0] += e * v0; acc[m][1] += e * v1;
                acc[m][2] += e * v2; acc[m][3] += e * v3;
            }
        }
    }

    const int slice = jq * 4 + w;   // 0..15
    #pragma unroll
    for (int m = 0; m < 4; ++m) {
        const size_t idx = ((size_t)((b * 2 + h) * 16 + slice)) * SS + row0 + m * 64;
        wsD[idx] = den[m];
        wsA[idx] = make_float4(acc[m][0], acc[m][1], acc[m][2], acc[m][3]);
    }
}

// Merge 16 slice-partials per (token, head), divide, closed-form quantum, Wo.
extern "C" __global__ __launch_bounds__(256)
void qa_quantum2(const float* __restrict__ wsD, const float4* __restrict__ wsA,
                 const float* __restrict__ Wo, float* __restrict__ out) {
    __shared__ float wo[64];
    const int tid = threadIdx.x;
    if (tid < 64) wo[tid] = Wo[tid];
    __syncthreads();

    const int g = blockIdx.x * 256 + tid;   // token 0..16383
    const int b = g >> 11, s = g & 2047;

    float tok[8];
    #pragma unroll
    for (int h = 0; h < 2; ++h) {
        float den = 0.f, a0 = 0.f, a1 = 0.f, a2 = 0.f, a3 = 0.f;
        #pragma unroll
        for (int sl = 0; sl < 16; ++sl) {
            const size_t idx = ((size_t)((b * 2 + h) * 16 + sl)) * SS + s;
            den += wsD[idx];
            const float4 p = wsA[idx];
            a0 += p.x; a1 += p.y; a2 += p.z; a3 += p.w;
        }
        const float inv = 1.f / den;
        tok[h * 4 + 0] = a0 * inv; tok[h * 4 + 1] = a1 * inv;
        tok[h * 4 + 2] = a2 * inv; tok[h * 4 + 3] = a3 * inv;
    }

    float c[8];
    #pragma unroll
    for (int ww = 0; ww < 8; ++ww) c[ww] = __cosf(tok[ww] + tok[ww & 3]);

    float z[8];
    float p = 1.f;
    #pragma unroll
    for (int qq = 1; qq < 8; ++qq) { p *= c[qq]; z[qq] = p; }
    z[0] = p;                       // c1..c7
    #pragma unroll
    for (int qq = 1; qq < 8; ++qq) z[qq] *= c[0];   // c0..cq

    float y[8];
    #pragma unroll
    for (int f = 0; f < 8; ++f) {
        float sum = 0.f;
        #pragma unroll
        for (int qq = 0; qq < 8; ++qq) sum += z[qq] * wo[f * 8 + qq];
        y[f] = sum;
    }
    float* op = out + (size_t)g * 8;
    *(float4*)op       = make_float4(y[0], y[1], y[2], y[3]);
    *(float4*)(op + 4) = make_float4(y[4], y[5], y[6], y[7]);
}

extern "C" void kernel_launch(void* const* d_in, const int* in_sizes, int n_in,
                              void* d_out, int out_size, void* d_ws, size_t ws_size,
                              hipStream_t stream) {
    const float* x  = (const float*)d_in[0];
    const float* Wq = (const float*)d_in[1];
    const float* Wk = (const float*)d_in[2];
    const float* Wv = (const float*)d_in[3];
    const float* Wo = (const float*)d_in[4];
    float* out = (float*)d_out;

    float*  wsD = (float*)d_ws;                        // 8*2*16*2048 floats = 2 MB
    float4* wsA = (float4*)((char*)d_ws + (8 * 2 * 16 * 2048) * sizeof(float)); // 8 MB

    qa_attn2<<<dim3(512), dim3(256), 0, stream>>>(x, Wq, Wk, Wv, wsD, wsA);
    qa_quantum2<<<dim3(64), dim3(256), 0, stream>>>(wsD, wsA, Wo, out);
}

// Round 3
// 87.238 us; speedup vs baseline: 1.1009x; 1.1009x over previous
//
#include <hip/hip_runtime.h>

// QuantumAttention: B=8, S=2048, E=8, H=2, D=4, NQ=8
//
// R1: broadcast-LDS per single row -> LDS-pipe bound (~38us; 24cyc/j-step per
//     wave serving 64 pairs).
// R2: readlane scheme FAILED (~45-50us): readlane is a VALU op (8/t-step for
//     4 pairs), 2 waves/SIMD, serial dot->exp chains exposed.
// R3: LDS broadcast amortized over M=8 rows/lane: LDS ~5us/CU, VALU-bound
//     floor ~12us with 8-row ILP.
//
// Quantum circuit closed-form: c_w = cos(tok[w]+tok[w%4]);
// z[0]=c1..c7, z[q>=1]=c0..cq. Softmax one-pass (|score|<~8, fp32 safe);
// 0.5*log2(e) folded into Wq so inner exp is bare v_exp_f32.

#define SS 2048
#define EE 8

// grid 512: bid = b<<6 | h<<5 | rt<<3 | jw. 256 threads = 4 waves.
// Block: rows rt*512..+511 (8 per lane), j-window jw*256..+255 (64 per wave).
extern "C" __global__ __launch_bounds__(256)
void qa_attn3(const float* __restrict__ x, const float* __restrict__ Wq,
              const float* __restrict__ Wk, const float* __restrict__ Wv,
              float* __restrict__ wsD, float4* __restrict__ wsA) {
    __shared__ float wrow[96];                    // wq'(scaled), wk, wv
    __shared__ __align__(16) float4 kv4[512];     // 256 j x {K4,V4} = 8 KB
    __shared__ __align__(16) float4 racc[4 * 512];// per-wave row partials, 32 KB
    __shared__ float rden[4 * 512];               // 8 KB

    const int bid = blockIdx.x;
    const int jw = bid & 7, rt = (bid >> 3) & 3, h = (bid >> 5) & 1, b = bid >> 6;
    const int tid = threadIdx.x, lane = tid & 63, w = tid >> 6;

    if (tid < 96) {
        const int grp = tid >> 5, d = (tid >> 3) & 3, e = tid & 7;
        const float* W = (grp == 0) ? Wq : (grp == 1 ? Wk : Wv);
        float val = W[(h * 4 + d) * EE + e];
        if (grp == 0) val *= 0.72134752044f;   // 0.5 * log2(e)
        wrow[tid] = val;
    }
    __syncthreads();

    // ---- stage K,V for the 256-j window (one j per thread) ----
    {
        const int j = jw * 256 + tid;
        const float* xp = x + ((size_t)(b * SS + j)) * EE;
        float xv[8];
        *(float4*)&xv[0] = *(const float4*)xp;
        *(float4*)&xv[4] = *(const float4*)(xp + 4);
        float kk[4], vv[4];
        #pragma unroll
        for (int d = 0; d < 4; ++d) {
            float sk = 0.f, sv = 0.f;
            #pragma unroll
            for (int e = 0; e < 8; ++e) {
                sk += xv[e] * wrow[32 + d * 8 + e];
                sv += xv[e] * wrow[64 + d * 8 + e];
            }
            kk[d] = sk; vv[d] = sv;
        }
        kv4[tid * 2]     = make_float4(kk[0], kk[1], kk[2], kk[3]);
        kv4[tid * 2 + 1] = make_float4(vv[0], vv[1], vv[2], vv[3]);
    }

    // ---- q' for this lane's 8 rows (needs only wrow) ----
    float q[8][4];
    const int row0 = rt * 512 + lane;
    #pragma unroll
    for (int m = 0; m < 8; ++m) {
        const float* xp = x + ((size_t)(b * SS + row0 + m * 64)) * EE;
        float xv[8];
        *(float4*)&xv[0] = *(const float4*)xp;
        *(float4*)&xv[4] = *(const float4*)(xp + 4);
        #pragma unroll
        for (int d = 0; d < 4; ++d) {
            float s = 0.f;
            #pragma unroll
            for (int e = 0; e < 8; ++e) s += xv[e] * wrow[d * 8 + e];
            q[m][d] = s;
        }
    }
    __syncthreads();

    // ---- 64-j slice for this wave, 8 rows per lane ----
    float den[8] = {};
    float acc[8][4] = {};
    const int jb = w * 64;
    #pragma unroll 2
    for (int jl = 0; jl < 64; ++jl) {
        const float4 kk = kv4[(jb + jl) * 2];      // wave-broadcast
        const float4 vv = kv4[(jb + jl) * 2 + 1];
        #pragma unroll
        for (int m = 0; m < 8; ++m) {
            const float s = q[m][0] * kk.x + q[m][1] * kk.y
                          + q[m][2] * kk.z + q[m][3] * kk.w;
            const float e = __builtin_amdgcn_exp2f(s);
            den[m] += e;
            acc[m][0] += e * vv.x; acc[m][1] += e * vv.y;
            acc[m][2] += e * vv.z; acc[m][3] += e * vv.w;
        }
    }

    // ---- block-reduce the 4 waves' partials per row ----
    #pragma unroll
    for (int m = 0; m < 8; ++m) {
        rden[w * 512 + lane + m * 64] = den[m];
        racc[w * 512 + lane + m * 64] =
            make_float4(acc[m][0], acc[m][1], acc[m][2], acc[m][3]);
    }
    __syncthreads();
    #pragma unroll
    for (int u = 0; u < 2; ++u) {
        const int r = tid + u * 256;   // row 0..511 within tile
        float d = rden[r] + rden[512 + r] + rden[1024 + r] + rden[1536 + r];
        float4 a0 = racc[r], a1 = racc[512 + r], a2 = racc[1024 + r], a3 = racc[1536 + r];
        float4 a = make_float4(a0.x + a1.x + a2.x + a3.x,
                               a0.y + a1.y + a2.y + a3.y,
                               a0.z + a1.z + a2.z + a3.z,
                               a0.w + a1.w + a2.w + a3.w);
        const size_t idx = ((size_t)((b * 2 + h) * 8 + jw)) * SS + rt * 512 + r;
        wsD[idx] = d;
        wsA[idx] = a;
    }
}

// Merge 8 window-partials per (token, head), divide, closed-form quantum, Wo.
extern "C" __global__ __launch_bounds__(256)
void qa_quantum3(const float* __restrict__ wsD, const float4* __restrict__ wsA,
                 const float* __restrict__ Wo, float* __restrict__ out) {
    __shared__ float wo[64];
    const int tid = threadIdx.x;
    if (tid < 64) wo[tid] = Wo[tid];
    __syncthreads();

    const int g = blockIdx.x * 256 + tid;   // token 0..16383
    const int b = g >> 11, s = g & 2047;

    float tok[8];
    #pragma unroll
    for (int h = 0; h < 2; ++h) {
        float den = 0.f, a0 = 0.f, a1 = 0.f, a2 = 0.f, a3 = 0.f;
        #pragma unroll
        for (int sl = 0; sl < 8; ++sl) {
            const size_t idx = ((size_t)((b * 2 + h) * 8 + sl)) * SS + s;
            den += wsD[idx];
            const float4 p = wsA[idx];
            a0 += p.x; a1 += p.y; a2 += p.z; a3 += p.w;
        }
        const float inv = 1.f / den;
        tok[h * 4 + 0] = a0 * inv; tok[h * 4 + 1] = a1 * inv;
        tok[h * 4 + 2] = a2 * inv; tok[h * 4 + 3] = a3 * inv;
    }

    float c[8];
    #pragma unroll
    for (int ww = 0; ww < 8; ++ww) c[ww] = __cosf(tok[ww] + tok[ww & 3]);

    float z[8];
    float p = 1.f;
    #pragma unroll
    for (int qq = 1; qq < 8; ++qq) { p *= c[qq]; z[qq] = p; }
    z[0] = p;                       // c1..c7
    #pragma unroll
    for (int qq = 1; qq < 8; ++qq) z[qq] *= c[0];   // c0..cq

    float y[8];
    #pragma unroll
    for (int f = 0; f < 8; ++f) {
        float sum = 0.f;
        #pragma unroll
        for (int qq = 0; qq < 8; ++qq) sum += z[qq] * wo[f * 8 + qq];
        y[f] = sum;
    }
    float* op = out + (size_t)g * 8;
    *(float4*)op       = make_float4(y[0], y[1], y[2], y[3]);
    *(float4*)(op + 4) = make_float4(y[4], y[5], y[6], y[7]);
}

extern "C" void kernel_launch(void* const* d_in, const int* in_sizes, int n_in,
                              void* d_out, int out_size, void* d_ws, size_t ws_size,
                              hipStream_t stream) {
    const float* x  = (const float*)d_in[0];
    const float* Wq = (const float*)d_in[1];
    const float* Wk = (const float*)d_in[2];
    const float* Wv = (const float*)d_in[3];
    const float* Wo = (const float*)d_in[4];
    float* out = (float*)d_out;

    float*  wsD = (float*)d_ws;                          // 16*8*2048 floats = 1 MB
    float4* wsA = (float4*)((char*)d_ws + (16 * 8 * 2048) * sizeof(float)); // 4 MB

    qa_attn3<<<dim3(512), dim3(256), 0, stream>>>(x, Wq, Wk, Wv, wsD, wsA);
    qa_quantum3<<<dim3(64), dim3(256), 0, stream>>>(wsD, wsA, Wo, out);
}